// Round 13
// baseline (1162.226 us; speedup 1.0000x reference)
//
#include <hip/hip_runtime.h>

#define B_ 8
#define S_ 2048
#define E_ 1024
#define H_ 1024

typedef __attribute__((ext_vector_type(8))) short bf16x8;
typedef __attribute__((ext_vector_type(4))) float f32x4;

__device__ inline short f2bf(float f) {
  unsigned u = __builtin_bit_cast(unsigned, f);
  unsigned r = u + 0x7FFFu + ((u >> 16) & 1u);   // RNE
  return (short)(r >> 16);
}
__device__ inline float bf2f(short s) {
  unsigned u = ((unsigned)(unsigned short)s) << 16;
  return __builtin_bit_cast(float, u);
}

__device__ inline void async16(const void* g, void* l) {
  __builtin_amdgcn_global_load_lds((const __attribute__((address_space(1))) void*)g,
                                   (__attribute__((address_space(3))) void*)l,
                                   16, 0, 0);
}

// ---------- prep: X fp32->bf16 (blocks 0..2047) + W^T bf16 (blocks 2048..2815)
__global__ __launch_bounds__(256)
void prep(const float* __restrict__ X, short* __restrict__ Xbf,
          const float* __restrict__ W0, const float* __restrict__ W1,
          const float* __restrict__ W2, short* __restrict__ Wt) {
  __shared__ __align__(16) float t[64][65];
  const int bid = blockIdx.x;
  if (bid < 2048) {
    const int n4 = (int)((size_t)B_ * S_ * E_ / 4);
    const int stride = 2048 * 256;
    for (int i = bid * 256 + threadIdx.x; i < n4; i += stride) {
      float4 v = ((const float4*)X)[i];
      short4 o;
      o.x = f2bf(v.x); o.y = f2bf(v.y); o.z = f2bf(v.z); o.w = f2bf(v.w);
      ((short4*)Xbf)[i] = o;
    }
    return;
  }
  const int idx = bid - 2048;            // 0..767
  const int zz = idx >> 8;               // 0..2
  const int rem = idx & 255;
  const float* W = (zz == 0) ? W0 : (zz == 1) ? W1 : W2;
  short* out = Wt + (size_t)zz * H_ * E_;
  const int h0 = (rem & 15) * 64, e0 = (rem >> 4) * 64;
  const int r = threadIdx.x >> 4;        // 0..15
  const int c = (threadIdx.x & 15) * 4;  // 0..60
#pragma unroll
  for (int p = 0; p < 4; ++p) {
    int rr = r + p * 16;
    float4 v = *(const float4*)&W[(size_t)(e0 + rr) * H_ + h0 + c];
    t[rr][c + 0] = v.x; t[rr][c + 1] = v.y; t[rr][c + 2] = v.z; t[rr][c + 3] = v.w;
  }
  __syncthreads();
#pragma unroll
  for (int p = 0; p < 4; ++p) {
    int rr = r + p * 16;  // h-local
    short4 o;
    o.x = f2bf(t[c + 0][rr]); o.y = f2bf(t[c + 1][rr]);
    o.z = f2bf(t[c + 2][rr]); o.w = f2bf(t[c + 3][rr]);
    *(short4*)&out[(size_t)(h0 + rr) * E_ + e0 + c] = o;
  }
}

#define BAR() asm volatile("s_barrier" ::: "memory")
#define VMC(n) asm volatile("s_waitcnt vmcnt(" #n ")" ::: "memory")

#define RD_B(buf, ks)                                                        \
  _Pragma("unroll")                                                          \
  for (int n = 0; n < 4; ++n)                                                \
    bfr[n] = *(const bf16x8*)(lBp + (buf) * 32768 + (ks) * 16384 +           \
                              ((wc * 64 + n * 16 + lr) << 6) + aCol)

#define RD_A(buf, ks, mh)                                                    \
  _Pragma("unroll")                                                          \
  for (int m = 0; m < 4; ++m)                                                \
    af[m] = *(const bf16x8*)(lAp + (buf) * 32768 + (ks) * 16384 +            \
                             ((wr * 128 + (mh) * 64 + m * 16 + lr) << 6) + aCol)

#define MFMA16(mh)                                                           \
  _Pragma("unroll")                                                          \
  for (int m = 0; m < 4; ++m) {                                              \
    _Pragma("unroll")                                                        \
    for (int n = 0; n < 4; ++n)                                              \
      acc[(mh) * 4 + m][n] = __builtin_amdgcn_mfma_f32_16x16x32_bf16(        \
          af[m], bfr[n], acc[(mh) * 4 + m][n], 0, 0, 0);                     \
  }

#define STAGE_A(buf, ks, kt) do {                                            \
    const short* _s = A + (size_t)(m0 + srow) * ldA + (kt) * 64 + (ks) * 32 + scol; \
    char* _d = (char*)lAp + (buf) * 32768 + (ks) * 16384 + wv * 1024;        \
    async16(_s, _d);                                                         \
    async16(_s + (size_t)128 * ldA, _d + 8192);                              \
  } while (0)

#define STAGE_B(buf, ks, kt) do {                                            \
    const short* _s = Bt + (size_t)(n0 + srow) * ldBt + (kt) * 64 + (ks) * 32 + scol; \
    char* _d = (char*)lBp + (buf) * 32768 + (ks) * 16384 + wv * 1024;        \
    async16(_s, _d);                                                         \
    async16(_s + (size_t)128 * ldBt, _d + 8192);                             \
  } while (0)

#define LGKM0() do {                                                         \
    asm volatile("s_waitcnt lgkmcnt(0)" ::: "memory");                       \
    __builtin_amdgcn_sched_barrier(0);                                       \
  } while (0)

// ======== proj: 256x256 single-buffered m97-style, 2 blocks/CU ==============
// +bias, out bf16: Q/K segs direct; V seg written TRANSPOSED to Vt.
// LDS 64 KB (A/B ks-halves [2][256][32], no double-buffer). Per K-tile:
// 8 global_load_lds -> vmcnt(0)+bar -> 4x{ds_reads, lgkm, 16 MFMA} -> bar.
// Drain covered by the sibling block (m114 mechanism, proven by sc128/pv128).
__global__ __launch_bounds__(512, 4)
void gemm8s(const short* __restrict__ A, const short* __restrict__ Bt,
            void* __restrict__ C0, void* __restrict__ C1, void* __restrict__ C2,
            const float* __restrict__ b0, const float* __restrict__ b1,
            const float* __restrict__ b2,
            int K, int ldA, int ldBt, int ldC) {
  int bx, by;
  {
    const int bid = blockIdx.x;            // 768 = 8 * 96
    int t = (bid & 7) * 96 + (bid >> 3);
    by = t / 12; bx = t % 12;
  }

  __shared__ __align__(16) short lmem[2 * 2 * 256 * 32];  // 64 KB
  const char* lAp = (const char*)lmem;
  const char* lBp = (const char*)lmem + 32768;

  const int tid = threadIdx.x;
  const int lane = tid & 63;
  const int wv = tid >> 6;            // 0..7
  const int wr = wv >> 2, wc = wv & 3;
  const int lr = lane & 15, kg = lane >> 4;
  const int m0 = by * 256, n0 = bx * 256;
  const int nt = K >> 6;              // 16

  const int aCol = (kg * 16) ^ ((lr & 8) << 2);
  const int srow = tid >> 2;
  const int scol = (((tid & 3) * 16) ^ (tid & 32)) >> 1;

  f32x4 acc[8][4];
#pragma unroll
  for (int m = 0; m < 8; ++m)
#pragma unroll
    for (int n = 0; n < 4; ++n) acc[m][n] = (f32x4){0.f, 0.f, 0.f, 0.f};
  bf16x8 bfr[4], af[4];

  for (int t = 0; t < nt; ++t) {
    STAGE_A(0, 0, t); STAGE_A(0, 1, t);
    STAGE_B(0, 0, t); STAGE_B(0, 1, t);
    VMC(0);
    BAR();
    RD_B(0, 0);
    RD_A(0, 0, 0);
    LGKM0();
    __builtin_amdgcn_s_setprio(1); MFMA16(0); __builtin_amdgcn_s_setprio(0);
    RD_A(0, 0, 1);
    LGKM0();
    __builtin_amdgcn_s_setprio(1); MFMA16(1); __builtin_amdgcn_s_setprio(0);
    RD_B(0, 1);
    RD_A(0, 1, 0);
    LGKM0();
    __builtin_amdgcn_s_setprio(1); MFMA16(0); __builtin_amdgcn_s_setprio(0);
    RD_A(0, 1, 1);
    LGKM0();
    __builtin_amdgcn_s_setprio(1); MFMA16(1); __builtin_amdgcn_s_setprio(0);
    BAR();
  }

  // Epilogue. D layout: col = lane&15, row = (lane>>4)*4+reg
  if ((n0 >> 10) == 2) {
    // V segment: write TRANSPOSED to Vt[z][h][s] via LDS bounce,
    // 4 sub-passes (p = col-half -> h, w = row-half -> s), tv [128][132].
    short* tv = (short*)lmem;
    const int zb = by >> 3;
    const int sb = (by & 7) * 256;
    short* VT = (short*)C2 + (size_t)zb * H_ * S_;
    const int hseg = n0 - 2048;
    __syncthreads();
#pragma unroll
    for (int p = 0; p < 2; ++p) {
#pragma unroll
      for (int w = 0; w < 2; ++w) {
        if ((wc >> 1) == p && wr == w) {   // 2 waves write this sub-pass
#pragma unroll
          for (int mq = 0; mq < 8; ++mq) {
            int sr = (mq >> 2) * 64 + (mq & 3) * 16 + kg * 4;  // 0..127 local
#pragma unroll
            for (int n = 0; n < 4; ++n) {
              int c = wc * 64 + n * 16 + lr;   // global col within tile
              float bb = b2[hseg + c];
              f32x4 v = acc[mq][n];
              short4 o;
              o.x = f2bf(v[0] + bb); o.y = f2bf(v[1] + bb);
              o.z = f2bf(v[2] + bb); o.w = f2bf(v[3] + bb);
              *(short4*)&tv[(c & 127) * 132 + sr] = o;
            }
          }
        }
        __syncthreads();
#pragma unroll
        for (int i = 0; i < 4; ++i) {        // 128 h x 128 s out, coalesced
          int chunk = i * 512 + tid;         // 0..2047
          int h = chunk >> 4, sc = (chunk & 15) * 8;
          bf16x8 v8 = *(const bf16x8*)&tv[h * 132 + sc];
          *(bf16x8*)&VT[(size_t)(hseg + p * 128 + h) * S_ + sb + w * 128 + sc] = v8;
        }
        __syncthreads();
      }
    }
    return;
  }
#pragma unroll
  for (int mq = 0; mq < 8; ++mq) {
    int rowb = m0 + wr * 128 + (mq >> 2) * 64 + (mq & 3) * 16 + kg * 4;
#pragma unroll
    for (int n = 0; n < 4; ++n) {
      int col = n0 + wc * 64 + n * 16 + lr;
      f32x4 v = acc[mq][n];
      int seg = n0 >> 10;  // block-uniform: 0=Q 1=K (V intercepted above)
      const float* bp = (seg == 0) ? b0 : b1;
      short* C = (short*)((seg == 0) ? C0 : C1);
      int cl = col & 1023;
      float bb = bp[cl];
#pragma unroll
      for (int r = 0; r < 4; ++r)
        C[(size_t)(rowb + r) * ldC + cl] = f2bf(v[r] + bb);
    }
  }
}

// ============ scores: 128x128 m97-style, 256 threads, 4 blocks/CU ===========
#define MFMA16Q()                                                            \
  _Pragma("unroll")                                                          \
  for (int m = 0; m < 4; ++m) {                                              \
    _Pragma("unroll")                                                        \
    for (int n = 0; n < 4; ++n)                                              \
      acc[m][n] = __builtin_amdgcn_mfma_f32_16x16x32_bf16(                   \
          af[m], bfr[n], acc[m][n], 0, 0, 0);                                \
  }

__global__ __launch_bounds__(256, 4)
void sc128(const short* __restrict__ Q, const short* __restrict__ Kb,
           short* __restrict__ P, float* __restrict__ Pl, float scale) {
  const int z = blockIdx.x & 7;          // one batch per XCD
  int rr0 = blockIdx.x >> 3;             // 0..135 over causal (by,bx)
  int by = 0, ac = 0;
  while (rr0 >= ac + by + 1) { ac += by + 1; ++by; }
  const int bx = rr0 - ac;
  const short* A  = Q  + (size_t)z * S_ * H_;
  const short* Bt = Kb + (size_t)z * S_ * H_;

  __shared__ __align__(16) short lA[2][128 * 32];   // 16 KB
  __shared__ __align__(16) short lB[2][128 * 32];   // 16 KB
  const char* lAp = (const char*)&lA[0][0];
  const char* lBp = (const char*)&lB[0][0];

  const int tid = threadIdx.x;
  const int lane = tid & 63;
  const int wv = tid >> 6;               // 0..3
  const int wr = wv >> 1, wc = wv & 1;   // 2M x 2N, wave tile 64x64
  const int lr = lane & 15, kg = lane >> 4;
  const int m0 = by * 128, n0 = bx * 128;

  const int aCol = (kg * 16) ^ ((lr & 8) << 2);
  const int srow = tid >> 2;                               // 0..63
  const int scol = (((tid & 3) * 16) ^ (tid & 32)) >> 1;

  f32x4 acc[4][4];
#pragma unroll
  for (int m = 0; m < 4; ++m)
#pragma unroll
    for (int n = 0; n < 4; ++n) acc[m][n] = (f32x4){0.f, 0.f, 0.f, 0.f};
  bf16x8 bfr[4], af[4];

  for (int t = 0; t < 16; ++t) {         // K = 1024
    const short* sA = A  + (size_t)(m0 + srow) * H_ + t * 64 + scol;
    const short* sB = Bt + (size_t)(n0 + srow) * H_ + t * 64 + scol;
#pragma unroll
    for (int ks = 0; ks < 2; ++ks) {
      char* dA = (char*)lAp + ks * 8192 + tid * 16;
      char* dB = (char*)lBp + ks * 8192 + tid * 16;
      async16(sA + ks * 32, dA);
      async16(sA + ks * 32 + (size_t)64 * H_, dA + 4096);
      async16(sB + ks * 32, dB);
      async16(sB + ks * 32 + (size_t)64 * H_, dB + 4096);
    }
    VMC(0);
    BAR();
#pragma unroll
    for (int ks = 0; ks < 2; ++ks) {
#pragma unroll
      for (int n = 0; n < 4; ++n)
        bfr[n] = *(const bf16x8*)(lBp + ks * 8192 +
                                  ((wc * 64 + n * 16 + lr) << 6) + aCol);
#pragma unroll
      for (int m = 0; m < 4; ++m)
        af[m] = *(const bf16x8*)(lAp + ks * 8192 +
                                 ((wr * 64 + m * 16 + lr) << 6) + aCol);
      asm volatile("s_waitcnt lgkmcnt(0)" ::: "memory");
      __builtin_amdgcn_sched_barrier(0);
      __builtin_amdgcn_s_setprio(1);
      MFMA16Q();
      __builtin_amdgcn_s_setprio(0);
    }
    BAR();
  }

  // Epilogue: P = exp(s) bf16 (masked on diag tile) + row-sum partial
  float* tmpL = (float*)lAp;                 // [128][2]
  short* C = P + (size_t)z * S_ * S_;
  const bool diag = (bx == by);
#pragma unroll
  for (int m = 0; m < 4; ++m) {
    int rt0 = wr * 64 + m * 16 + kg * 4;
#pragma unroll
    for (int r = 0; r < 4; ++r) {
      int rt = rt0 + r;
      float se = 0.f;
#pragma unroll
      for (int n = 0; n < 4; ++n) {
        int c = wc * 64 + n * 16 + lr;
        bool ok = !diag || (c <= rt);
        short sh = ok ? f2bf(__expf(acc[m][n][r] * scale)) : (short)0;
        se += bf2f(sh);
        C[(size_t)(m0 + rt) * S_ + n0 + c] = sh;
      }
#pragma unroll
      for (int o = 1; o < 16; o <<= 1) se += __shfl_xor(se, o);
      if (lr == 0) tmpL[rt * 2 + wc] = se;
    }
  }
  __syncthreads();
  if (tid < 128) {
    float l = tmpL[tid * 2 + 0] + tmpL[tid * 2 + 1];
    Pl[((size_t)z * 16 + bx) * S_ + m0 + tid] = l;
  }
}

// ============ PV: 128x256 m97-style, 2 blocks/CU, balanced pairing ==========
__global__ __launch_bounds__(512, 4)
void pv128(const short* __restrict__ A, const short* __restrict__ Bt,
           float* __restrict__ C0, const float* __restrict__ Pl) {
  const int z = blockIdx.x & 7;          // one batch per XCD
  const int rr0 = blockIdx.x >> 3;       // 0..63
  const int j = rr0 >> 2;                // 0..15
  const int by = (j < 8) ? (15 - j) : (j - 8);   // pair (by, 15-by) per CU
  const int bx = rr0 & 3;
  const short* Ap  = A  + (size_t)z * S_ * S_;
  const short* Btp = Bt + (size_t)z * H_ * S_;

  __shared__ __align__(16) short lA[2][128 * 32];   // 16 KB
  __shared__ __align__(16) short lB[2][256 * 32];   // 32 KB
  __shared__ float sLi[128];
  const char* lAp = (const char*)&lA[0][0];
  const char* lBp = (const char*)&lB[0][0];

  const int tid = threadIdx.x;
  const int lane = tid & 63;
  const int wv = tid >> 6;
  const int wr = wv >> 2, wc = wv & 3;   // 2M x 4N, wave tile 64x64
  const int lr = lane & 15, kg = lane >> 4;
  const int m0 = by * 128, n0 = bx * 256;
  const int nt = (by + 1) * 2;           // K = (by+1)*128, BK=64

  const int aCol = (kg * 16) ^ ((lr & 8) << 2);
  const int srow = tid >> 2;                               // 0..127
  const int scol = (((tid & 3) * 16) ^ (tid & 32)) >> 1;

  if (tid < 128) {                       // per-row 1/l from 128-col partials
    float l = 0.f;
    for (int kt = 0; kt <= by; ++kt)
      l += Pl[((size_t)z * 16 + kt) * S_ + m0 + tid];
    sLi[tid] = 1.f / l;
  }

  f32x4 acc[4][4];
#pragma unroll
  for (int m = 0; m < 4; ++m)
#pragma unroll
    for (int n = 0; n < 4; ++n) acc[m][n] = (f32x4){0.f, 0.f, 0.f, 0.f};
  bf16x8 bfr[4], af[4];

  for (int t = 0; t < nt; ++t) {
    {
      const short* sA = Ap  + (size_t)(m0 + srow) * S_ + t * 64 + scol;
      const short* sB = Btp + (size_t)(n0 + srow) * S_ + t * 64 + scol;
      char* dA = (char*)lAp + tid * 16;
      char* dB = (char*)lBp + tid * 16;
      async16(sA, dA);                                 // A ks0
      async16(sA + 32, dA + 8192);                     // A ks1
      async16(sB, dB);                                 // B ks0 rows 0..127
      async16(sB + (size_t)128 * S_, dB + 8192);       // B ks0 rows 128..255
      async16(sB + 32, dB + 16384);                    // B ks1 rows 0..127
      async16(sB + (size_t)128 * S_ + 32, dB + 24576); // B ks1 rows 128..255
    }
    VMC(0);
    BAR();
#pragma unroll
    for (int ks = 0; ks < 2; ++ks) {
#pragma unroll
      for (int n = 0; n < 4; ++n)
        bfr[n] = *(const bf16x8*)(lBp + ks * 16384 +
                                  ((wc * 64 + n * 16 + lr) << 6) + aCol);
#pragma unroll
      for (int m = 0; m < 4; ++m)
        af[m] = *(const bf16x8*)(lAp + ks * 8192 +
                                 ((wr * 64 + m * 16 + lr) << 6) + aCol);
      asm volatile("s_waitcnt lgkmcnt(0)" ::: "memory");
      __builtin_amdgcn_sched_barrier(0);
      __builtin_amdgcn_s_setprio(1);
      MFMA16Q();
      __builtin_amdgcn_s_setprio(0);
    }
    BAR();
  }

  // Epilogue: scale by 1/l, fp32 final write
  float* C = C0 + (size_t)z * S_ * H_;
#pragma unroll
  for (int m = 0; m < 4; ++m) {
    int rl = wr * 64 + m * 16 + kg * 4;
    f32x4 liv = *(const f32x4*)&sLi[rl];
    int rowb = m0 + rl;
#pragma unroll
    for (int n = 0; n < 4; ++n) {
      int col = n0 + wc * 64 + n * 16 + lr;
      f32x4 v = acc[m][n];
#pragma unroll
      for (int r = 0; r < 4; ++r)
        C[(size_t)(rowb + r) * H_ + col] = v[r] * liv[r];
    }
  }
}

extern "C" void kernel_launch(void* const* d_in, const int* in_sizes, int n_in,
                              void* d_out, int out_size, void* d_ws, size_t ws_size,
                              hipStream_t stream) {
  const float* X  = (const float*)d_in[0];
  const float* Wq = (const float*)d_in[1];
  const float* bq = (const float*)d_in[2];
  const float* Wk = (const float*)d_in[3];
  const float* bk = (const float*)d_in[4];
  const float* Wv = (const float*)d_in[5];
  const float* bv = (const float*)d_in[6];

  // Workspace layout (~166.3 MB), overlays:
  //   [0,64MB)   P bf16 [B][S][S]  -- early: Xbf [0,32MB)
  //   [64,96)    Q bf16, [96,128) K bf16, [128,160) Vt bf16
  //   [160,166.3) Wt bf16 x3 (proj only) -- later: row-sum partials Pl
  char* ws = (char*)d_ws;
  const size_t MB = 1024ull * 1024ull;
  short* Pbuf = (short*)ws;
  short* Xbf  = (short*)ws;
  short* Q    = (short*)(ws + 64 * MB);
  short* Kb   = (short*)(ws + 96 * MB);
  short* Vt   = (short*)(ws + 128 * MB);
  short* Wt   = (short*)(ws + 160 * MB);
  float* Pl   = (float*)(ws + 160 * MB);   // [z*16+kt128][2048] f32 = 1 MB

  // 1) prep: X -> bf16 + W -> W^T bf16, one launch
  prep<<<2816, 256, 0, stream>>>(X, Xbf, Wq, Wk, Wv, Wt);
  // 2) fused QKV projection, single-buffered 2-blk/CU; V transposed to Vt
  gemm8s<<<768, 512, 0, stream>>>(
      Xbf, Wt, Q, Kb, Vt, bq, bk, bv, E_, E_, E_, H_);
  // 3) P = exp(Q K^T / 32) bf16 + 128-col row-sum partials (1088 = 136 x 8)
  sc128<<<1088, 256, 0, stream>>>(Q, Kb, Pbuf, Pl, 0.03125f);
  // 4) out = (P @ V) * (1/l) fp32 (512 blocks, balanced by-pairing)
  pv128<<<512, 512, 0, stream>>>(Pbuf, Vt, (float*)d_out, Pl);
}

// Round 14
// 243.566 us; speedup vs baseline: 4.7717x; 4.7717x over previous
//
#include <hip/hip_runtime.h>

#define B_ 8
#define S_ 2048
#define E_ 1024
#define H_ 1024

typedef __attribute__((ext_vector_type(8))) short bf16x8;
typedef __attribute__((ext_vector_type(4))) float f32x4;

__device__ inline short f2bf(float f) {
  unsigned u = __builtin_bit_cast(unsigned, f);
  unsigned r = u + 0x7FFFu + ((u >> 16) & 1u);   // RNE
  return (short)(r >> 16);
}
__device__ inline float bf2f(short s) {
  unsigned u = ((unsigned)(unsigned short)s) << 16;
  return __builtin_bit_cast(float, u);
}

__device__ inline void async16(const void* g, void* l) {
  __builtin_amdgcn_global_load_lds((const __attribute__((address_space(1))) void*)g,
                                   (__attribute__((address_space(3))) void*)l,
                                   16, 0, 0);
}

// ---------- prep: X fp32->bf16 (blocks 0..2047) + W^T bf16 (blocks 2048..2815)
__global__ __launch_bounds__(256)
void prep(const float* __restrict__ X, short* __restrict__ Xbf,
          const float* __restrict__ W0, const float* __restrict__ W1,
          const float* __restrict__ W2, short* __restrict__ Wt) {
  __shared__ __align__(16) float t[64][65];
  const int bid = blockIdx.x;
  if (bid < 2048) {
    const int n4 = (int)((size_t)B_ * S_ * E_ / 4);
    const int stride = 2048 * 256;
    for (int i = bid * 256 + threadIdx.x; i < n4; i += stride) {
      float4 v = ((const float4*)X)[i];
      short4 o;
      o.x = f2bf(v.x); o.y = f2bf(v.y); o.z = f2bf(v.z); o.w = f2bf(v.w);
      ((short4*)Xbf)[i] = o;
    }
    return;
  }
  const int idx = bid - 2048;            // 0..767
  const int zz = idx >> 8;               // 0..2
  const int rem = idx & 255;
  const float* W = (zz == 0) ? W0 : (zz == 1) ? W1 : W2;
  short* out = Wt + (size_t)zz * H_ * E_;
  const int h0 = (rem & 15) * 64, e0 = (rem >> 4) * 64;
  const int r = threadIdx.x >> 4;        // 0..15
  const int c = (threadIdx.x & 15) * 4;  // 0..60
#pragma unroll
  for (int p = 0; p < 4; ++p) {
    int rr = r + p * 16;
    float4 v = *(const float4*)&W[(size_t)(e0 + rr) * H_ + h0 + c];
    t[rr][c + 0] = v.x; t[rr][c + 1] = v.y; t[rr][c + 2] = v.z; t[rr][c + 3] = v.w;
  }
  __syncthreads();
#pragma unroll
  for (int p = 0; p < 4; ++p) {
    int rr = r + p * 16;  // h-local
    short4 o;
    o.x = f2bf(t[c + 0][rr]); o.y = f2bf(t[c + 1][rr]);
    o.z = f2bf(t[c + 2][rr]); o.w = f2bf(t[c + 3][rr]);
    *(short4*)&out[(size_t)(h0 + rr) * E_ + e0 + c] = o;
  }
}

// ======================= 8-phase 256x256 GEMM (proj only) ====================
#define BAR() asm volatile("s_barrier" ::: "memory")
#define VMC(n) asm volatile("s_waitcnt vmcnt(" #n ")" ::: "memory")

#define RD_B(buf, ks)                                                        \
  _Pragma("unroll")                                                          \
  for (int n = 0; n < 4; ++n)                                                \
    bfr[n] = *(const bf16x8*)(lBp + (buf) * 32768 + (ks) * 16384 +           \
                              ((wc * 64 + n * 16 + lr) << 6) + aCol)

#define RD_A(buf, ks, mh)                                                    \
  _Pragma("unroll")                                                          \
  for (int m = 0; m < 4; ++m)                                                \
    af[m] = *(const bf16x8*)(lAp + (buf) * 32768 + (ks) * 16384 +            \
                             ((wr * 128 + (mh) * 64 + m * 16 + lr) << 6) + aCol)

#define MFMA16(mh)                                                           \
  _Pragma("unroll")                                                          \
  for (int m = 0; m < 4; ++m) {                                              \
    _Pragma("unroll")                                                        \
    for (int n = 0; n < 4; ++n)                                              \
      acc[(mh) * 4 + m][n] = __builtin_amdgcn_mfma_f32_16x16x32_bf16(        \
          af[m], bfr[n], acc[(mh) * 4 + m][n], 0, 0, 0);                     \
  }

#define STAGE_A(buf, ks, kt) do {                                            \
    const short* _s = A + (size_t)(m0 + srow) * ldA + (kt) * 64 + (ks) * 32 + scol; \
    char* _d = (char*)lAp + (buf) * 32768 + (ks) * 16384 + wv * 1024;        \
    async16(_s, _d);                                                         \
    async16(_s + (size_t)128 * ldA, _d + 8192);                              \
  } while (0)

#define STAGE_B(buf, ks, kt) do {                                            \
    const short* _s = Bt + (size_t)(n0 + srow) * ldBt + (kt) * 64 + (ks) * 32 + scol; \
    char* _d = (char*)lBp + (buf) * 32768 + (ks) * 16384 + wv * 1024;        \
    async16(_s, _d);                                                         \
    async16(_s + (size_t)128 * ldBt, _d + 8192);                             \
  } while (0)

#define PHASE(buf, ks, mh, STG, WT) do {                                     \
    if ((mh) == 0) { RD_B(buf, ks); }                                        \
    RD_A(buf, ks, mh);                                                       \
    STG;                                                                     \
    WT;                                                                      \
    BAR();                                                                   \
    asm volatile("s_waitcnt lgkmcnt(0)" ::: "memory");                       \
    __builtin_amdgcn_sched_barrier(0);                                       \
    __builtin_amdgcn_s_setprio(1);                                           \
    MFMA16(mh);                                                              \
    __builtin_amdgcn_s_setprio(0);                                           \
    BAR();                                                                   \
  } while (0)

// +bias, out bf16: Q/K segs direct; V seg written TRANSPOSED to Vt.
__global__ __launch_bounds__(512, 2)
void gemm8(const short* __restrict__ A, const short* __restrict__ Bt,
           void* __restrict__ C0, void* __restrict__ C1, void* __restrict__ C2,
           const float* __restrict__ b0, const float* __restrict__ b1,
           const float* __restrict__ b2,
           int K, int ldA, int ldBt, int ldC) {
  int bx, by;
  {
    const int bid = blockIdx.x;            // 768 = 8 * 96
    int t = (bid & 7) * 96 + (bid >> 3);
    by = t / 12; bx = t % 12;
  }

  __shared__ __align__(16) short lA[2][2][256 * 32];  // 64 KB
  __shared__ __align__(16) short lB[2][2][256 * 32];  // 64 KB
  const char* lAp = (const char*)&lA[0][0][0];
  const char* lBp = (const char*)&lB[0][0][0];

  const int tid = threadIdx.x;
  const int lane = tid & 63;
  const int wv = tid >> 6;            // 0..7
  const int wr = wv >> 2, wc = wv & 3;
  const int lr = lane & 15, kg = lane >> 4;
  const int m0 = by * 256, n0 = bx * 256;
  const int nt = K >> 6;
  const int nIter = nt >> 1;

  const int aCol = (kg * 16) ^ ((lr & 8) << 2);
  const int srow = tid >> 2;
  const int scol = (((tid & 3) * 16) ^ (tid & 32)) >> 1;

  f32x4 acc[8][4];
#pragma unroll
  for (int m = 0; m < 8; ++m)
#pragma unroll
    for (int n = 0; n < 4; ++n) acc[m][n] = (f32x4){0.f, 0.f, 0.f, 0.f};
  bf16x8 bfr[4], af[4];

  STAGE_B(0, 0, 0); STAGE_A(0, 0, 0); STAGE_B(0, 1, 0); STAGE_A(0, 1, 0);
  STAGE_B(1, 0, 1); STAGE_A(1, 0, 1); STAGE_B(1, 1, 1);
  VMC(6);
  BAR();

  for (int i = 0; i < nIter; ++i) {
    const int T = 2 * i;
    const bool lastI = (i == nIter - 1);
    PHASE(0, 0, 0, STAGE_A(1, 1, T + 1), (void)0);
    PHASE(0, 0, 1, if (!lastI) { STAGE_B(0, 0, T + 2); }, (void)0);
    PHASE(0, 1, 0, if (!lastI) { STAGE_A(0, 0, T + 2); }, (void)0);
    PHASE(0, 1, 1, if (!lastI) { STAGE_B(0, 1, T + 2); },
          if (lastI) { VMC(0); } else { VMC(6); });
    PHASE(1, 0, 0, if (!lastI) { STAGE_A(0, 1, T + 2); }, (void)0);
    PHASE(1, 0, 1, if (!lastI) { STAGE_B(1, 0, T + 3); }, (void)0);
    PHASE(1, 1, 0, if (!lastI) { STAGE_A(1, 0, T + 3); }, (void)0);
    PHASE(1, 1, 1, if (!lastI) { STAGE_B(1, 1, T + 3); },
          if (!lastI) { VMC(6); });
  }

  // Epilogue. D layout: col = lane&15, row = (lane>>4)*4+reg
  if ((n0 >> 10) == 2) {
    // V segment: write TRANSPOSED to Vt[z][h][s] via LDS bounce.
    short* tv = (short*)lAp;               // [128][264] shorts
    const int zb = by >> 3;
    const int sb = (by & 7) * 256;
    short* VT = (short*)C2 + (size_t)zb * H_ * S_;
    const int hseg = n0 - 2048;
#pragma unroll
    for (int p = 0; p < 2; ++p) {
      if ((wc >> 1) == p) {
#pragma unroll
        for (int mq = 0; mq < 8; ++mq) {
          int sr = wr * 128 + (mq >> 2) * 64 + (mq & 3) * 16 + kg * 4;
#pragma unroll
          for (int n = 0; n < 4; ++n) {
            int c = wc * 64 + n * 16 + lr;     // 0..255
            float bb = b2[hseg + c];
            f32x4 v = acc[mq][n];
            short4 o;
            o.x = f2bf(v[0] + bb); o.y = f2bf(v[1] + bb);
            o.z = f2bf(v[2] + bb); o.w = f2bf(v[3] + bb);
            *(short4*)&tv[(c & 127) * 264 + sr] = o;
          }
        }
      }
      __syncthreads();
#pragma unroll
      for (int i = 0; i < 8; ++i) {
        int chunk = i * 512 + tid;
        int h = chunk >> 5, sc = (chunk & 31) * 8;
        bf16x8 v8 = *(const bf16x8*)&tv[h * 264 + sc];
        *(bf16x8*)&VT[(size_t)(hseg + p * 128 + h) * S_ + sb + sc] = v8;
      }
      __syncthreads();
    }
    return;
  }
#pragma unroll
  for (int mq = 0; mq < 8; ++mq) {
    int rowb = m0 + wr * 128 + (mq >> 2) * 64 + (mq & 3) * 16 + kg * 4;
#pragma unroll
    for (int n = 0; n < 4; ++n) {
      int col = n0 + wc * 64 + n * 16 + lr;
      f32x4 v = acc[mq][n];
      int seg = n0 >> 10;  // block-uniform: 0=Q 1=K (V intercepted above)
      const float* bp = (seg == 0) ? b0 : b1;
      short* C = (short*)((seg == 0) ? C0 : C1);
      int cl = col & 1023;
      float bb = bp[cl];
#pragma unroll
      for (int r = 0; r < 4; ++r)
        C[(size_t)(rowb + r) * ldC + cl] = f2bf(v[r] + bb);
    }
  }
}

// ============ scores: 128x128 m97-style, 256 threads, 4 blocks/CU ===========
#define MFMA16Q()                                                            \
  _Pragma("unroll")                                                          \
  for (int m = 0; m < 4; ++m) {                                              \
    _Pragma("unroll")                                                        \
    for (int n = 0; n < 4; ++n)                                              \
      acc[m][n] = __builtin_amdgcn_mfma_f32_16x16x32_bf16(                   \
          af[m], bfr[n], acc[m][n], 0, 0, 0);                                \
  }

__global__ __launch_bounds__(256, 4)
void sc128(const short* __restrict__ Q, const short* __restrict__ Kb,
           short* __restrict__ P, float* __restrict__ Pl, float scale) {
  const int z = blockIdx.x & 7;          // one batch per XCD
  int rr0 = blockIdx.x >> 3;             // 0..135 over causal (by,bx)
  int by = 0, ac = 0;
  while (rr0 >= ac + by + 1) { ac += by + 1; ++by; }
  const int bx = rr0 - ac;
  const short* A  = Q  + (size_t)z * S_ * H_;
  const short* Bt = Kb + (size_t)z * S_ * H_;

  __shared__ __align__(16) short lA[2][128 * 32];   // 16 KB
  __shared__ __align__(16) short lB[2][128 * 32];   // 16 KB
  const char* lAp = (const char*)&lA[0][0];
  const char* lBp = (const char*)&lB[0][0];

  const int tid = threadIdx.x;
  const int lane = tid & 63;
  const int wv = tid >> 6;               // 0..3
  const int wr = wv >> 1, wc = wv & 1;   // 2M x 2N, wave tile 64x64
  const int lr = lane & 15, kg = lane >> 4;
  const int m0 = by * 128, n0 = bx * 128;

  const int aCol = (kg * 16) ^ ((lr & 8) << 2);
  const int srow = tid >> 2;                               // 0..63
  const int scol = (((tid & 3) * 16) ^ (tid & 32)) >> 1;

  f32x4 acc[4][4];
#pragma unroll
  for (int m = 0; m < 4; ++m)
#pragma unroll
    for (int n = 0; n < 4; ++n) acc[m][n] = (f32x4){0.f, 0.f, 0.f, 0.f};
  bf16x8 bfr[4], af[4];

  for (int t = 0; t < 16; ++t) {         // K = 1024
    const short* sA = A  + (size_t)(m0 + srow) * H_ + t * 64 + scol;
    const short* sB = Bt + (size_t)(n0 + srow) * H_ + t * 64 + scol;
#pragma unroll
    for (int ks = 0; ks < 2; ++ks) {
      char* dA = (char*)lAp + ks * 8192 + tid * 16;
      char* dB = (char*)lBp + ks * 8192 + tid * 16;
      async16(sA + ks * 32, dA);
      async16(sA + ks * 32 + (size_t)64 * H_, dA + 4096);
      async16(sB + ks * 32, dB);
      async16(sB + ks * 32 + (size_t)64 * H_, dB + 4096);
    }
    VMC(0);
    BAR();
#pragma unroll
    for (int ks = 0; ks < 2; ++ks) {
#pragma unroll
      for (int n = 0; n < 4; ++n)
        bfr[n] = *(const bf16x8*)(lBp + ks * 8192 +
                                  ((wc * 64 + n * 16 + lr) << 6) + aCol);
#pragma unroll
      for (int m = 0; m < 4; ++m)
        af[m] = *(const bf16x8*)(lAp + ks * 8192 +
                                 ((wr * 64 + m * 16 + lr) << 6) + aCol);
      asm volatile("s_waitcnt lgkmcnt(0)" ::: "memory");
      __builtin_amdgcn_sched_barrier(0);
      __builtin_amdgcn_s_setprio(1);
      MFMA16Q();
      __builtin_amdgcn_s_setprio(0);
    }
    BAR();
  }

  // Epilogue: P = exp(s) bf16 (masked on diag tile) + row-sum partial
  float* tmpL = (float*)lAp;                 // [128][2]
  short* C = P + (size_t)z * S_ * S_;
  const bool diag = (bx == by);
#pragma unroll
  for (int m = 0; m < 4; ++m) {
    int rt0 = wr * 64 + m * 16 + kg * 4;
#pragma unroll
    for (int r = 0; r < 4; ++r) {
      int rt = rt0 + r;
      float se = 0.f;
#pragma unroll
      for (int n = 0; n < 4; ++n) {
        int c = wc * 64 + n * 16 + lr;
        bool ok = !diag || (c <= rt);
        short sh = ok ? f2bf(__expf(acc[m][n][r] * scale)) : (short)0;
        se += bf2f(sh);
        C[(size_t)(m0 + rt) * S_ + n0 + c] = sh;
      }
#pragma unroll
      for (int o = 1; o < 16; o <<= 1) se += __shfl_xor(se, o);
      if (lr == 0) tmpL[rt * 2 + wc] = se;
    }
  }
  __syncthreads();
  if (tid < 128) {
    float l = tmpL[tid * 2 + 0] + tmpL[tid * 2 + 1];
    Pl[((size_t)z * 16 + bx) * S_ + m0 + tid] = l;
  }
}

// ============ PV: 128x256 m97-style, 2 blocks/CU, balanced pairing ==========
__global__ __launch_bounds__(512, 4)
void pv128(const short* __restrict__ A, const short* __restrict__ Bt,
           float* __restrict__ C0, const float* __restrict__ Pl) {
  const int z = blockIdx.x & 7;          // one batch per XCD
  const int rr0 = blockIdx.x >> 3;       // 0..63
  const int j = rr0 >> 2;                // 0..15
  const int by = (j < 8) ? (15 - j) : (j - 8);   // pair (by, 15-by) per CU
  const int bx = rr0 & 3;
  const short* Ap  = A  + (size_t)z * S_ * S_;
  const short* Btp = Bt + (size_t)z * H_ * S_;

  __shared__ __align__(16) short lA[2][128 * 32];   // 16 KB
  __shared__ __align__(16) short lB[2][256 * 32];   // 32 KB
  __shared__ float sLi[128];
  const char* lAp = (const char*)&lA[0][0];
  const char* lBp = (const char*)&lB[0][0];

  const int tid = threadIdx.x;
  const int lane = tid & 63;
  const int wv = tid >> 6;
  const int wr = wv >> 2, wc = wv & 3;   // 2M x 4N, wave tile 64x64
  const int lr = lane & 15, kg = lane >> 4;
  const int m0 = by * 128, n0 = bx * 256;
  const int nt = (by + 1) * 2;           // K = (by+1)*128, BK=64

  const int aCol = (kg * 16) ^ ((lr & 8) << 2);
  const int srow = tid >> 2;                               // 0..127
  const int scol = (((tid & 3) * 16) ^ (tid & 32)) >> 1;

  if (tid < 128) {                       // per-row 1/l from 128-col partials
    float l = 0.f;
    for (int kt = 0; kt <= by; ++kt)
      l += Pl[((size_t)z * 16 + kt) * S_ + m0 + tid];
    sLi[tid] = 1.f / l;
  }

  f32x4 acc[4][4];
#pragma unroll
  for (int m = 0; m < 4; ++m)
#pragma unroll
    for (int n = 0; n < 4; ++n) acc[m][n] = (f32x4){0.f, 0.f, 0.f, 0.f};
  bf16x8 bfr[4], af[4];

  for (int t = 0; t < nt; ++t) {
    {
      const short* sA = Ap  + (size_t)(m0 + srow) * S_ + t * 64 + scol;
      const short* sB = Btp + (size_t)(n0 + srow) * S_ + t * 64 + scol;
      char* dA = (char*)lAp + tid * 16;
      char* dB = (char*)lBp + tid * 16;
      async16(sA, dA);                                 // A ks0
      async16(sA + 32, dA + 8192);                     // A ks1
      async16(sB, dB);                                 // B ks0 rows 0..127
      async16(sB + (size_t)128 * S_, dB + 8192);       // B ks0 rows 128..255
      async16(sB + 32, dB + 16384);                    // B ks1 rows 0..127
      async16(sB + (size_t)128 * S_ + 32, dB + 24576); // B ks1 rows 128..255
    }
    VMC(0);
    BAR();
#pragma unroll
    for (int ks = 0; ks < 2; ++ks) {
#pragma unroll
      for (int n = 0; n < 4; ++n)
        bfr[n] = *(const bf16x8*)(lBp + ks * 16384 +
                                  ((wc * 64 + n * 16 + lr) << 6) + aCol);
#pragma unroll
      for (int m = 0; m < 4; ++m)
        af[m] = *(const bf16x8*)(lAp + ks * 8192 +
                                 ((wr * 64 + m * 16 + lr) << 6) + aCol);
      asm volatile("s_waitcnt lgkmcnt(0)" ::: "memory");
      __builtin_amdgcn_sched_barrier(0);
      __builtin_amdgcn_s_setprio(1);
      MFMA16Q();
      __builtin_amdgcn_s_setprio(0);
    }
    BAR();
  }

  // Epilogue: scale by 1/l, fp32 final write
  float* C = C0 + (size_t)z * S_ * H_;
#pragma unroll
  for (int m = 0; m < 4; ++m) {
    int rl = wr * 64 + m * 16 + kg * 4;
    f32x4 liv = *(const f32x4*)&sLi[rl];
    int rowb = m0 + rl;
#pragma unroll
    for (int n = 0; n < 4; ++n) {
      int col = n0 + wc * 64 + n * 16 + lr;
      f32x4 v = acc[m][n];
#pragma unroll
      for (int r = 0; r < 4; ++r)
        C[(size_t)(rowb + r) * H_ + col] = v[r] * liv[r];
    }
  }
}

extern "C" void kernel_launch(void* const* d_in, const int* in_sizes, int n_in,
                              void* d_out, int out_size, void* d_ws, size_t ws_size,
                              hipStream_t stream) {
  const float* X  = (const float*)d_in[0];
  const float* Wq = (const float*)d_in[1];
  const float* bq = (const float*)d_in[2];
  const float* Wk = (const float*)d_in[3];
  const float* bk = (const float*)d_in[4];
  const float* Wv = (const float*)d_in[5];
  const float* bv = (const float*)d_in[6];

  // Workspace layout (~166.3 MB), overlays:
  //   [0,64MB)   P bf16 [B][S][S]  -- early: Xbf [0,32MB)
  //   [64,96)    Q bf16, [96,128) K bf16, [128,160) Vt bf16
  //   [160,166.3) Wt bf16 x3 (proj only) -- later: row-sum partials Pl
  char* ws = (char*)d_ws;
  const size_t MB = 1024ull * 1024ull;
  short* Pbuf = (short*)ws;
  short* Xbf  = (short*)ws;
  short* Q    = (short*)(ws + 64 * MB);
  short* Kb   = (short*)(ws + 96 * MB);
  short* Vt   = (short*)(ws + 128 * MB);
  short* Wt   = (short*)(ws + 160 * MB);
  float* Pl   = (float*)(ws + 160 * MB);   // [z*16+kt128][2048] f32 = 1 MB

  // 1) prep: X -> bf16 + W -> W^T bf16, one launch
  prep<<<2816, 256, 0, stream>>>(X, Xbf, Wq, Wk, Wv, Wt);
  // 2) fused QKV projection (8-phase dbuf, (512,2)); V transposed to Vt
  gemm8<<<768, 512, 0, stream>>>(
      Xbf, Wt, Q, Kb, Vt, bq, bk, bv, E_, E_, E_, H_);
  // 3) P = exp(Q K^T / 32) bf16 + 128-col row-sum partials (1088 = 136 x 8)
  sc128<<<1088, 256, 0, stream>>>(Q, Kb, Pbuf, Pl, 0.03125f);
  // 4) out = (P @ V) * (1/l) fp32 (512 blocks, balanced by-pairing)
  pv128<<<512, 512, 0, stream>>>(Pbuf, Vt, (float*)d_out, Pl);
}

// Round 15
// 238.850 us; speedup vs baseline: 4.8659x; 1.0197x over previous
//
#include <hip/hip_runtime.h>

#define B_ 8
#define S_ 2048
#define E_ 1024
#define H_ 1024

typedef __attribute__((ext_vector_type(8))) short bf16x8;
typedef __attribute__((ext_vector_type(4))) float f32x4;

__device__ inline short f2bf(float f) {
  unsigned u = __builtin_bit_cast(unsigned, f);
  unsigned r = u + 0x7FFFu + ((u >> 16) & 1u);   // RNE
  return (short)(r >> 16);
}
__device__ inline float bf2f(short s) {
  unsigned u = ((unsigned)(unsigned short)s) << 16;
  return __builtin_bit_cast(float, u);
}

__device__ inline void async16(const void* g, void* l) {
  __builtin_amdgcn_global_load_lds((const __attribute__((address_space(1))) void*)g,
                                   (__attribute__((address_space(3))) void*)l,
                                   16, 0, 0);
}

// ---------- prep: X fp32->bf16 (blocks 0..2047) + W^T bf16 (blocks 2048..2815)
__global__ __launch_bounds__(256)
void prep(const float* __restrict__ X, short* __restrict__ Xbf,
          const float* __restrict__ W0, const float* __restrict__ W1,
          const float* __restrict__ W2, short* __restrict__ Wt) {
  __shared__ __align__(16) float t[64][65];
  const int bid = blockIdx.x;
  if (bid < 2048) {
    const int n4 = (int)((size_t)B_ * S_ * E_ / 4);
    const int stride = 2048 * 256;
    for (int i = bid * 256 + threadIdx.x; i < n4; i += stride) {
      float4 v = ((const float4*)X)[i];
      short4 o;
      o.x = f2bf(v.x); o.y = f2bf(v.y); o.z = f2bf(v.z); o.w = f2bf(v.w);
      ((short4*)Xbf)[i] = o;
    }
    return;
  }
  const int idx = bid - 2048;            // 0..767
  const int zz = idx >> 8;               // 0..2
  const int rem = idx & 255;
  const float* W = (zz == 0) ? W0 : (zz == 1) ? W1 : W2;
  short* out = Wt + (size_t)zz * H_ * E_;
  const int h0 = (rem & 15) * 64, e0 = (rem >> 4) * 64;
  const int r = threadIdx.x >> 4;        // 0..15
  const int c = (threadIdx.x & 15) * 4;  // 0..60
#pragma unroll
  for (int p = 0; p < 4; ++p) {
    int rr = r + p * 16;
    float4 v = *(const float4*)&W[(size_t)(e0 + rr) * H_ + h0 + c];
    t[rr][c + 0] = v.x; t[rr][c + 1] = v.y; t[rr][c + 2] = v.z; t[rr][c + 3] = v.w;
  }
  __syncthreads();
#pragma unroll
  for (int p = 0; p < 4; ++p) {
    int rr = r + p * 16;  // h-local
    short4 o;
    o.x = f2bf(t[c + 0][rr]); o.y = f2bf(t[c + 1][rr]);
    o.z = f2bf(t[c + 2][rr]); o.w = f2bf(t[c + 3][rr]);
    *(short4*)&out[(size_t)(h0 + rr) * E_ + e0 + c] = o;
  }
}

// ======================= 8-phase 256x256 GEMM (proj only) ====================
#define BAR() asm volatile("s_barrier" ::: "memory")
#define VMC(n) asm volatile("s_waitcnt vmcnt(" #n ")" ::: "memory")

#define RD_B(buf, ks)                                                        \
  _Pragma("unroll")                                                          \
  for (int n = 0; n < 4; ++n)                                                \
    bfr[n] = *(const bf16x8*)(lBp + (buf) * 32768 + (ks) * 16384 +           \
                              ((wc * 64 + n * 16 + lr) << 6) + aCol)

#define RD_A(buf, ks, mh)                                                    \
  _Pragma("unroll")                                                          \
  for (int m = 0; m < 4; ++m)                                                \
    af[m] = *(const bf16x8*)(lAp + (buf) * 32768 + (ks) * 16384 +            \
                             ((wr * 128 + (mh) * 64 + m * 16 + lr) << 6) + aCol)

#define MFMA16(mh)                                                           \
  _Pragma("unroll")                                                          \
  for (int m = 0; m < 4; ++m) {                                              \
    _Pragma("unroll")                                                        \
    for (int n = 0; n < 4; ++n)                                              \
      acc[(mh) * 4 + m][n] = __builtin_amdgcn_mfma_f32_16x16x32_bf16(        \
          af[m], bfr[n], acc[(mh) * 4 + m][n], 0, 0, 0);                     \
  }

#define STAGE_A(buf, ks, kt) do {                                            \
    const short* _s = A + (size_t)(m0 + srow) * ldA + (kt) * 64 + (ks) * 32 + scol; \
    char* _d = (char*)lAp + (buf) * 32768 + (ks) * 16384 + wv * 1024;        \
    async16(_s, _d);                                                         \
    async16(_s + (size_t)128 * ldA, _d + 8192);                              \
  } while (0)

#define STAGE_B(buf, ks, kt) do {                                            \
    const short* _s = Bt + (size_t)(n0 + srow) * ldBt + (kt) * 64 + (ks) * 32 + scol; \
    char* _d = (char*)lBp + (buf) * 32768 + (ks) * 16384 + wv * 1024;        \
    async16(_s, _d);                                                         \
    async16(_s + (size_t)128 * ldBt, _d + 8192);                             \
  } while (0)

#define PHASE(buf, ks, mh, STG, WT) do {                                     \
    if ((mh) == 0) { RD_B(buf, ks); }                                        \
    RD_A(buf, ks, mh);                                                       \
    STG;                                                                     \
    WT;                                                                      \
    BAR();                                                                   \
    asm volatile("s_waitcnt lgkmcnt(0)" ::: "memory");                       \
    __builtin_amdgcn_sched_barrier(0);                                       \
    __builtin_amdgcn_s_setprio(1);                                           \
    MFMA16(mh);                                                              \
    __builtin_amdgcn_s_setprio(0);                                           \
    BAR();                                                                   \
  } while (0)

// +bias, out bf16: Q/K segs direct; V seg written TRANSPOSED to Vt.
__global__ __launch_bounds__(512, 2)
void gemm8(const short* __restrict__ A, const short* __restrict__ Bt,
           void* __restrict__ C0, void* __restrict__ C1, void* __restrict__ C2,
           const float* __restrict__ b0, const float* __restrict__ b1,
           const float* __restrict__ b2,
           int K, int ldA, int ldBt, int ldC) {
  int bx, by;
  {
    const int bid = blockIdx.x;            // 768 = 8 * 96
    int t = (bid & 7) * 96 + (bid >> 3);
    by = t / 12; bx = t % 12;
  }

  __shared__ __align__(16) short lA[2][2][256 * 32];  // 64 KB
  __shared__ __align__(16) short lB[2][2][256 * 32];  // 64 KB
  const char* lAp = (const char*)&lA[0][0][0];
  const char* lBp = (const char*)&lB[0][0][0];

  const int tid = threadIdx.x;
  const int lane = tid & 63;
  const int wv = tid >> 6;            // 0..7
  const int wr = wv >> 2, wc = wv & 3;
  const int lr = lane & 15, kg = lane >> 4;
  const int m0 = by * 256, n0 = bx * 256;
  const int nt = K >> 6;
  const int nIter = nt >> 1;

  const int aCol = (kg * 16) ^ ((lr & 8) << 2);
  const int srow = tid >> 2;
  const int scol = (((tid & 3) * 16) ^ (tid & 32)) >> 1;

  f32x4 acc[8][4];
#pragma unroll
  for (int m = 0; m < 8; ++m)
#pragma unroll
    for (int n = 0; n < 4; ++n) acc[m][n] = (f32x4){0.f, 0.f, 0.f, 0.f};
  bf16x8 bfr[4], af[4];

  STAGE_B(0, 0, 0); STAGE_A(0, 0, 0); STAGE_B(0, 1, 0); STAGE_A(0, 1, 0);
  STAGE_B(1, 0, 1); STAGE_A(1, 0, 1); STAGE_B(1, 1, 1);
  VMC(6);
  BAR();

  for (int i = 0; i < nIter; ++i) {
    const int T = 2 * i;
    const bool lastI = (i == nIter - 1);
    PHASE(0, 0, 0, STAGE_A(1, 1, T + 1), (void)0);
    PHASE(0, 0, 1, if (!lastI) { STAGE_B(0, 0, T + 2); }, (void)0);
    PHASE(0, 1, 0, if (!lastI) { STAGE_A(0, 0, T + 2); }, (void)0);
    PHASE(0, 1, 1, if (!lastI) { STAGE_B(0, 1, T + 2); },
          if (lastI) { VMC(0); } else { VMC(6); });
    PHASE(1, 0, 0, if (!lastI) { STAGE_A(0, 1, T + 2); }, (void)0);
    PHASE(1, 0, 1, if (!lastI) { STAGE_B(1, 0, T + 3); }, (void)0);
    PHASE(1, 1, 0, if (!lastI) { STAGE_A(1, 0, T + 3); }, (void)0);
    PHASE(1, 1, 1, if (!lastI) { STAGE_B(1, 1, T + 3); },
          if (!lastI) { VMC(6); });
  }

  // Epilogue. D layout: col = lane&15, row = (lane>>4)*4+reg
  if ((n0 >> 10) == 2) {
    // V segment: write TRANSPOSED to Vt[z][h][s] via LDS bounce.
    short* tv = (short*)lAp;               // [128][264] shorts
    const int zb = by >> 3;
    const int sb = (by & 7) * 256;
    short* VT = (short*)C2 + (size_t)zb * H_ * S_;
    const int hseg = n0 - 2048;
#pragma unroll
    for (int p = 0; p < 2; ++p) {
      if ((wc >> 1) == p) {
#pragma unroll
        for (int mq = 0; mq < 8; ++mq) {
          int sr = wr * 128 + (mq >> 2) * 64 + (mq & 3) * 16 + kg * 4;
#pragma unroll
          for (int n = 0; n < 4; ++n) {
            int c = wc * 64 + n * 16 + lr;     // 0..255
            float bb = b2[hseg + c];
            f32x4 v = acc[mq][n];
            short4 o;
            o.x = f2bf(v[0] + bb); o.y = f2bf(v[1] + bb);
            o.z = f2bf(v[2] + bb); o.w = f2bf(v[3] + bb);
            *(short4*)&tv[(c & 127) * 264 + sr] = o;
          }
        }
      }
      __syncthreads();
#pragma unroll
      for (int i = 0; i < 8; ++i) {
        int chunk = i * 512 + tid;
        int h = chunk >> 5, sc = (chunk & 31) * 8;
        bf16x8 v8 = *(const bf16x8*)&tv[h * 264 + sc];
        *(bf16x8*)&VT[(size_t)(hseg + p * 128 + h) * S_ + sb + sc] = v8;
      }
      __syncthreads();
    }
    return;
  }
#pragma unroll
  for (int mq = 0; mq < 8; ++mq) {
    int rowb = m0 + wr * 128 + (mq >> 2) * 64 + (mq & 3) * 16 + kg * 4;
#pragma unroll
    for (int n = 0; n < 4; ++n) {
      int col = n0 + wc * 64 + n * 16 + lr;
      f32x4 v = acc[mq][n];
      int seg = n0 >> 10;  // block-uniform: 0=Q 1=K (V intercepted above)
      const float* bp = (seg == 0) ? b0 : b1;
      short* C = (short*)((seg == 0) ? C0 : C1);
      int cl = col & 1023;
      float bb = bp[cl];
#pragma unroll
      for (int r = 0; r < 4; ++r)
        C[(size_t)(rowb + r) * ldC + cl] = f2bf(v[r] + bb);
    }
  }
}

// ============ scores: 128x128 m97-style, 256 threads, 4 blocks/CU ===========
#define MFMA16Q()                                                            \
  _Pragma("unroll")                                                          \
  for (int m = 0; m < 4; ++m) {                                              \
    _Pragma("unroll")                                                        \
    for (int n = 0; n < 4; ++n)                                              \
      acc[m][n] = __builtin_amdgcn_mfma_f32_16x16x32_bf16(                   \
          af[m], bfr[n], acc[m][n], 0, 0, 0);                                \
  }

__global__ __launch_bounds__(256, 4)
void sc128(const short* __restrict__ Q, const short* __restrict__ Kb,
           short* __restrict__ P, float* __restrict__ Pl, float scale) {
  const int z = blockIdx.x & 7;          // one batch per XCD
  int rr0 = blockIdx.x >> 3;             // 0..135 over causal (by,bx)
  int by = 0, ac = 0;
  while (rr0 >= ac + by + 1) { ac += by + 1; ++by; }
  const int bx = rr0 - ac;
  const short* A  = Q  + (size_t)z * S_ * H_;
  const short* Bt = Kb + (size_t)z * S_ * H_;

  __shared__ __align__(16) short lA[2][128 * 32];   // 16 KB
  __shared__ __align__(16) short lB[2][128 * 32];   // 16 KB
  const char* lAp = (const char*)&lA[0][0];
  const char* lBp = (const char*)&lB[0][0];

  const int tid = threadIdx.x;
  const int lane = tid & 63;
  const int wv = tid >> 6;               // 0..3
  const int wr = wv >> 1, wc = wv & 1;   // 2M x 2N, wave tile 64x64
  const int lr = lane & 15, kg = lane >> 4;
  const int m0 = by * 128, n0 = bx * 128;

  const int aCol = (kg * 16) ^ ((lr & 8) << 2);
  const int srow = tid >> 2;                               // 0..63
  const int scol = (((tid & 3) * 16) ^ (tid & 32)) >> 1;

  f32x4 acc[4][4];
#pragma unroll
  for (int m = 0; m < 4; ++m)
#pragma unroll
    for (int n = 0; n < 4; ++n) acc[m][n] = (f32x4){0.f, 0.f, 0.f, 0.f};
  bf16x8 bfr[4], af[4];

  for (int t = 0; t < 16; ++t) {         // K = 1024
    const short* sA = A  + (size_t)(m0 + srow) * H_ + t * 64 + scol;
    const short* sB = Bt + (size_t)(n0 + srow) * H_ + t * 64 + scol;
#pragma unroll
    for (int ks = 0; ks < 2; ++ks) {
      char* dA = (char*)lAp + ks * 8192 + tid * 16;
      char* dB = (char*)lBp + ks * 8192 + tid * 16;
      async16(sA + ks * 32, dA);
      async16(sA + ks * 32 + (size_t)64 * H_, dA + 4096);
      async16(sB + ks * 32, dB);
      async16(sB + ks * 32 + (size_t)64 * H_, dB + 4096);
    }
    VMC(0);
    BAR();
#pragma unroll
    for (int ks = 0; ks < 2; ++ks) {
#pragma unroll
      for (int n = 0; n < 4; ++n)
        bfr[n] = *(const bf16x8*)(lBp + ks * 8192 +
                                  ((wc * 64 + n * 16 + lr) << 6) + aCol);
#pragma unroll
      for (int m = 0; m < 4; ++m)
        af[m] = *(const bf16x8*)(lAp + ks * 8192 +
                                 ((wr * 64 + m * 16 + lr) << 6) + aCol);
      asm volatile("s_waitcnt lgkmcnt(0)" ::: "memory");
      __builtin_amdgcn_sched_barrier(0);
      __builtin_amdgcn_s_setprio(1);
      MFMA16Q();
      __builtin_amdgcn_s_setprio(0);
    }
    BAR();
  }

  // Epilogue: P = exp(s) bf16 (masked on diag tile) + row-sum partial
  float* tmpL = (float*)lAp;                 // [128][2]
  short* C = P + (size_t)z * S_ * S_;
  const bool diag = (bx == by);
#pragma unroll
  for (int m = 0; m < 4; ++m) {
    int rt0 = wr * 64 + m * 16 + kg * 4;
#pragma unroll
    for (int r = 0; r < 4; ++r) {
      int rt = rt0 + r;
      float se = 0.f;
#pragma unroll
      for (int n = 0; n < 4; ++n) {
        int c = wc * 64 + n * 16 + lr;
        bool ok = !diag || (c <= rt);
        short sh = ok ? f2bf(__expf(acc[m][n][r] * scale)) : (short)0;
        se += bf2f(sh);
        C[(size_t)(m0 + rt) * S_ + n0 + c] = sh;
      }
#pragma unroll
      for (int o = 1; o < 16; o <<= 1) se += __shfl_xor(se, o);
      if (lr == 0) tmpL[rt * 2 + wc] = se;
    }
  }
  __syncthreads();
  if (tid < 128) {
    float l = tmpL[tid * 2 + 0] + tmpL[tid * 2 + 1];
    Pl[((size_t)z * 16 + bx) * S_ + m0 + tid] = l;
  }
}

// ====== PV: 128x128 m97-style, 4 blocks/CU, all-resident balanced quads =====
// Grid 1024 = 8z x 8bx x 16by (exactly 4 blocks/CU, all co-resident).
// by = (j<8)?(15-j):(j-8) with j=rr0>>3: co-resident quads {j,j+4,j+8,j+12}
// have by+1 sums == 34 -> per-CU K-work exactly constant. K = (by+1)*128.
// Out fp32 * (1/l) from 128-col Pl partials.
__global__ __launch_bounds__(256, 4)
void pv128q(const short* __restrict__ A, const short* __restrict__ Bt,
            float* __restrict__ C0, const float* __restrict__ Pl) {
  const int z = blockIdx.x & 7;          // one batch per XCD
  const int rr0 = blockIdx.x >> 3;       // 0..127
  const int bx = rr0 & 7;
  const int j = rr0 >> 3;                // 0..15
  const int by = (j < 8) ? (15 - j) : (j - 8);
  const short* Ap  = A  + (size_t)z * S_ * S_;
  const short* Btp = Bt + (size_t)z * H_ * S_;

  __shared__ __align__(16) short lA[2][128 * 32];   // 16 KB
  __shared__ __align__(16) short lB[2][128 * 32];   // 16 KB
  __shared__ float sLi[128];
  const char* lAp = (const char*)&lA[0][0];
  const char* lBp = (const char*)&lB[0][0];

  const int tid = threadIdx.x;
  const int lane = tid & 63;
  const int wv = tid >> 6;               // 0..3
  const int wr = wv >> 1, wc = wv & 1;   // 2M x 2N, wave tile 64x64
  const int lr = lane & 15, kg = lane >> 4;
  const int m0 = by * 128, n0 = bx * 128;
  const int nt = (by + 1) * 2;           // K = (by+1)*128, BK=64

  const int aCol = (kg * 16) ^ ((lr & 8) << 2);
  const int srow = tid >> 2;                               // 0..63
  const int scol = (((tid & 3) * 16) ^ (tid & 32)) >> 1;

  if (tid < 128) {                       // per-row 1/l from 128-col partials
    float l = 0.f;
    for (int kt = 0; kt <= by; ++kt)
      l += Pl[((size_t)z * 16 + kt) * S_ + m0 + tid];
    sLi[tid] = 1.f / l;
  }

  f32x4 acc[4][4];
#pragma unroll
  for (int m = 0; m < 4; ++m)
#pragma unroll
    for (int n = 0; n < 4; ++n) acc[m][n] = (f32x4){0.f, 0.f, 0.f, 0.f};
  bf16x8 bfr[4], af[4];

  for (int t = 0; t < nt; ++t) {
    const short* sA = Ap  + (size_t)(m0 + srow) * S_ + t * 64 + scol;
    const short* sB = Btp + (size_t)(n0 + srow) * S_ + t * 64 + scol;
#pragma unroll
    for (int ks = 0; ks < 2; ++ks) {
      char* dA = (char*)lAp + ks * 8192 + tid * 16;
      char* dB = (char*)lBp + ks * 8192 + tid * 16;
      async16(sA + ks * 32, dA);
      async16(sA + ks * 32 + (size_t)64 * S_, dA + 4096);
      async16(sB + ks * 32, dB);
      async16(sB + ks * 32 + (size_t)64 * S_, dB + 4096);
    }
    VMC(0);
    BAR();
#pragma unroll
    for (int ks = 0; ks < 2; ++ks) {
#pragma unroll
      for (int n = 0; n < 4; ++n)
        bfr[n] = *(const bf16x8*)(lBp + ks * 8192 +
                                  ((wc * 64 + n * 16 + lr) << 6) + aCol);
#pragma unroll
      for (int m = 0; m < 4; ++m)
        af[m] = *(const bf16x8*)(lAp + ks * 8192 +
                                 ((wr * 64 + m * 16 + lr) << 6) + aCol);
      asm volatile("s_waitcnt lgkmcnt(0)" ::: "memory");
      __builtin_amdgcn_sched_barrier(0);
      __builtin_amdgcn_s_setprio(1);
      MFMA16Q();
      __builtin_amdgcn_s_setprio(0);
    }
    BAR();
  }

  // Epilogue: scale by 1/l, fp32 final write
  float* C = C0 + (size_t)z * S_ * H_;
#pragma unroll
  for (int m = 0; m < 4; ++m) {
    int rl = wr * 64 + m * 16 + kg * 4;
    f32x4 liv = *(const f32x4*)&sLi[rl];
    int rowb = m0 + rl;
#pragma unroll
    for (int n = 0; n < 4; ++n) {
      int col = n0 + wc * 64 + n * 16 + lr;
      f32x4 v = acc[m][n];
#pragma unroll
      for (int r = 0; r < 4; ++r)
        C[(size_t)(rowb + r) * H_ + col] = v[r] * liv[r];
    }
  }
}

extern "C" void kernel_launch(void* const* d_in, const int* in_sizes, int n_in,
                              void* d_out, int out_size, void* d_ws, size_t ws_size,
                              hipStream_t stream) {
  const float* X  = (const float*)d_in[0];
  const float* Wq = (const float*)d_in[1];
  const float* bq = (const float*)d_in[2];
  const float* Wk = (const float*)d_in[3];
  const float* bk = (const float*)d_in[4];
  const float* Wv = (const float*)d_in[5];
  const float* bv = (const float*)d_in[6];

  // Workspace layout (~166.3 MB), overlays:
  //   [0,64MB)   P bf16 [B][S][S]  -- early: Xbf [0,32MB)
  //   [64,96)    Q bf16, [96,128) K bf16, [128,160) Vt bf16
  //   [160,166.3) Wt bf16 x3 (proj only) -- later: row-sum partials Pl
  char* ws = (char*)d_ws;
  const size_t MB = 1024ull * 1024ull;
  short* Pbuf = (short*)ws;
  short* Xbf  = (short*)ws;
  short* Q    = (short*)(ws + 64 * MB);
  short* Kb   = (short*)(ws + 96 * MB);
  short* Vt   = (short*)(ws + 128 * MB);
  short* Wt   = (short*)(ws + 160 * MB);
  float* Pl   = (float*)(ws + 160 * MB);   // [z*16+kt128][2048] f32 = 1 MB

  // 1) prep: X -> bf16 + W -> W^T bf16, one launch
  prep<<<2816, 256, 0, stream>>>(X, Xbf, Wq, Wk, Wv, Wt);
  // 2) fused QKV projection (8-phase dbuf, (512,2)); V transposed to Vt
  gemm8<<<768, 512, 0, stream>>>(
      Xbf, Wt, Q, Kb, Vt, bq, bk, bv, E_, E_, E_, H_);
  // 3) P = exp(Q K^T / 32) bf16 + 128-col row-sum partials (1088 = 136 x 8)
  sc128<<<1088, 256, 0, stream>>>(Q, Kb, Pbuf, Pl, 0.03125f);
  // 4) out = (P @ V) * (1/l) fp32 (1024 all-resident, balanced quads)
  pv128q<<<1024, 256, 0, stream>>>(Pbuf, Vt, (float*)d_out, Pl);
}

// Round 16
// 234.416 us; speedup vs baseline: 4.9580x; 1.0189x over previous
//
#include <hip/hip_runtime.h>

#define B_ 8
#define S_ 2048
#define E_ 1024
#define H_ 1024

typedef __attribute__((ext_vector_type(8))) short bf16x8;
typedef __attribute__((ext_vector_type(4))) float f32x4;

__device__ inline short f2bf(float f) {
  unsigned u = __builtin_bit_cast(unsigned, f);
  unsigned r = u + 0x7FFFu + ((u >> 16) & 1u);   // RNE
  return (short)(r >> 16);
}
__device__ inline float bf2f(short s) {
  unsigned u = ((unsigned)(unsigned short)s) << 16;
  return __builtin_bit_cast(float, u);
}

__device__ inline void async16(const void* g, void* l) {
  __builtin_amdgcn_global_load_lds((const __attribute__((address_space(1))) void*)g,
                                   (__attribute__((address_space(3))) void*)l,
                                   16, 0, 0);
}

// ---------- prep: X fp32->bf16 (blocks 0..2047) + W^T bf16 (blocks 2048..2815)
__global__ __launch_bounds__(256)
void prep(const float* __restrict__ X, short* __restrict__ Xbf,
          const float* __restrict__ W0, const float* __restrict__ W1,
          const float* __restrict__ W2, short* __restrict__ Wt) {
  __shared__ __align__(16) float t[64][65];
  const int bid = blockIdx.x;
  if (bid < 2048) {
    const int n4 = (int)((size_t)B_ * S_ * E_ / 4);
    const int stride = 2048 * 256;
    for (int i = bid * 256 + threadIdx.x; i < n4; i += stride) {
      float4 v = ((const float4*)X)[i];
      short4 o;
      o.x = f2bf(v.x); o.y = f2bf(v.y); o.z = f2bf(v.z); o.w = f2bf(v.w);
      ((short4*)Xbf)[i] = o;
    }
    return;
  }
  const int idx = bid - 2048;            // 0..767
  const int zz = idx >> 8;               // 0..2
  const int rem = idx & 255;
  const float* W = (zz == 0) ? W0 : (zz == 1) ? W1 : W2;
  short* out = Wt + (size_t)zz * H_ * E_;
  const int h0 = (rem & 15) * 64, e0 = (rem >> 4) * 64;
  const int r = threadIdx.x >> 4;        // 0..15
  const int c = (threadIdx.x & 15) * 4;  // 0..60
#pragma unroll
  for (int p = 0; p < 4; ++p) {
    int rr = r + p * 16;
    float4 v = *(const float4*)&W[(size_t)(e0 + rr) * H_ + h0 + c];
    t[rr][c + 0] = v.x; t[rr][c + 1] = v.y; t[rr][c + 2] = v.z; t[rr][c + 3] = v.w;
  }
  __syncthreads();
#pragma unroll
  for (int p = 0; p < 4; ++p) {
    int rr = r + p * 16;  // h-local
    short4 o;
    o.x = f2bf(t[c + 0][rr]); o.y = f2bf(t[c + 1][rr]);
    o.z = f2bf(t[c + 2][rr]); o.w = f2bf(t[c + 3][rr]);
    *(short4*)&out[(size_t)(h0 + rr) * E_ + e0 + c] = o;
  }
}

// ======================= 8-phase 256x256 GEMM (proj only) ====================
#define BAR() asm volatile("s_barrier" ::: "memory")
#define VMC(n) asm volatile("s_waitcnt vmcnt(" #n ")" ::: "memory")

#define RD_B(buf, ks)                                                        \
  _Pragma("unroll")                                                          \
  for (int n = 0; n < 4; ++n)                                                \
    bfr[n] = *(const bf16x8*)(lBp + (buf) * 32768 + (ks) * 16384 +           \
                              ((wc * 64 + n * 16 + lr) << 6) + aCol)

#define RD_A(buf, ks, mh)                                                    \
  _Pragma("unroll")                                                          \
  for (int m = 0; m < 4; ++m)                                                \
    af[m] = *(const bf16x8*)(lAp + (buf) * 32768 + (ks) * 16384 +            \
                             ((wr * 128 + (mh) * 64 + m * 16 + lr) << 6) + aCol)

#define MFMA16(mh)                                                           \
  _Pragma("unroll")                                                          \
  for (int m = 0; m < 4; ++m) {                                              \
    _Pragma("unroll")                                                        \
    for (int n = 0; n < 4; ++n)                                              \
      acc[(mh) * 4 + m][n] = __builtin_amdgcn_mfma_f32_16x16x32_bf16(        \
          af[m], bfr[n], acc[(mh) * 4 + m][n], 0, 0, 0);                     \
  }

#define STAGE_A(buf, ks, kt) do {                                            \
    const short* _s = A + (size_t)(m0 + srow) * ldA + (kt) * 64 + (ks) * 32 + scol; \
    char* _d = (char*)lAp + (buf) * 32768 + (ks) * 16384 + wv * 1024;        \
    async16(_s, _d);                                                         \
    async16(_s + (size_t)128 * ldA, _d + 8192);                              \
  } while (0)

#define STAGE_B(buf, ks, kt) do {                                            \
    const short* _s = Bt + (size_t)(n0 + srow) * ldBt + (kt) * 64 + (ks) * 32 + scol; \
    char* _d = (char*)lBp + (buf) * 32768 + (ks) * 16384 + wv * 1024;        \
    async16(_s, _d);                                                         \
    async16(_s + (size_t)128 * ldBt, _d + 8192);                             \
  } while (0)

#define PHASE(buf, ks, mh, STG, WT) do {                                     \
    if ((mh) == 0) { RD_B(buf, ks); }                                        \
    RD_A(buf, ks, mh);                                                       \
    STG;                                                                     \
    WT;                                                                      \
    BAR();                                                                   \
    asm volatile("s_waitcnt lgkmcnt(0)" ::: "memory");                       \
    __builtin_amdgcn_sched_barrier(0);                                       \
    __builtin_amdgcn_s_setprio(1);                                           \
    MFMA16(mh);                                                              \
    __builtin_amdgcn_s_setprio(0);                                           \
    BAR();                                                                   \
  } while (0)

// +bias, out bf16: Q/K segs direct; V seg written TRANSPOSED to Vt.
__global__ __launch_bounds__(512, 2)
void gemm8(const short* __restrict__ A, const short* __restrict__ Bt,
           void* __restrict__ C0, void* __restrict__ C1, void* __restrict__ C2,
           const float* __restrict__ b0, const float* __restrict__ b1,
           const float* __restrict__ b2,
           int K, int ldA, int ldBt, int ldC) {
  int bx, by;
  {
    const int bid = blockIdx.x;            // 768 = 8 * 96
    int t = (bid & 7) * 96 + (bid >> 3);
    by = t / 12; bx = t % 12;
  }

  __shared__ __align__(16) short lA[2][2][256 * 32];  // 64 KB
  __shared__ __align__(16) short lB[2][2][256 * 32];  // 64 KB
  const char* lAp = (const char*)&lA[0][0][0];
  const char* lBp = (const char*)&lB[0][0][0];

  const int tid = threadIdx.x;
  const int lane = tid & 63;
  const int wv = tid >> 6;            // 0..7
  const int wr = wv >> 2, wc = wv & 3;
  const int lr = lane & 15, kg = lane >> 4;
  const int m0 = by * 256, n0 = bx * 256;
  const int nt = K >> 6;
  const int nIter = nt >> 1;

  const int aCol = (kg * 16) ^ ((lr & 8) << 2);
  const int srow = tid >> 2;
  const int scol = (((tid & 3) * 16) ^ (tid & 32)) >> 1;

  f32x4 acc[8][4];
#pragma unroll
  for (int m = 0; m < 8; ++m)
#pragma unroll
    for (int n = 0; n < 4; ++n) acc[m][n] = (f32x4){0.f, 0.f, 0.f, 0.f};
  bf16x8 bfr[4], af[4];

  STAGE_B(0, 0, 0); STAGE_A(0, 0, 0); STAGE_B(0, 1, 0); STAGE_A(0, 1, 0);
  STAGE_B(1, 0, 1); STAGE_A(1, 0, 1); STAGE_B(1, 1, 1);
  VMC(6);
  BAR();

  for (int i = 0; i < nIter; ++i) {
    const int T = 2 * i;
    const bool lastI = (i == nIter - 1);
    PHASE(0, 0, 0, STAGE_A(1, 1, T + 1), (void)0);
    PHASE(0, 0, 1, if (!lastI) { STAGE_B(0, 0, T + 2); }, (void)0);
    PHASE(0, 1, 0, if (!lastI) { STAGE_A(0, 0, T + 2); }, (void)0);
    PHASE(0, 1, 1, if (!lastI) { STAGE_B(0, 1, T + 2); },
          if (lastI) { VMC(0); } else { VMC(6); });
    PHASE(1, 0, 0, if (!lastI) { STAGE_A(0, 1, T + 2); }, (void)0);
    PHASE(1, 0, 1, if (!lastI) { STAGE_B(1, 0, T + 3); }, (void)0);
    PHASE(1, 1, 0, if (!lastI) { STAGE_A(1, 0, T + 3); }, (void)0);
    PHASE(1, 1, 1, if (!lastI) { STAGE_B(1, 1, T + 3); },
          if (!lastI) { VMC(6); });
  }

  // Epilogue. D layout: col = lane&15, row = (lane>>4)*4+reg
  if ((n0 >> 10) == 2) {
    // V segment: write TRANSPOSED to Vt[z][h][s] via LDS bounce.
    short* tv = (short*)lAp;               // [128][264] shorts
    const int zb = by >> 3;
    const int sb = (by & 7) * 256;
    short* VT = (short*)C2 + (size_t)zb * H_ * S_;
    const int hseg = n0 - 2048;
#pragma unroll
    for (int p = 0; p < 2; ++p) {
      if ((wc >> 1) == p) {
#pragma unroll
        for (int mq = 0; mq < 8; ++mq) {
          int sr = wr * 128 + (mq >> 2) * 64 + (mq & 3) * 16 + kg * 4;
#pragma unroll
          for (int n = 0; n < 4; ++n) {
            int c = wc * 64 + n * 16 + lr;     // 0..255
            float bb = b2[hseg + c];
            f32x4 v = acc[mq][n];
            short4 o;
            o.x = f2bf(v[0] + bb); o.y = f2bf(v[1] + bb);
            o.z = f2bf(v[2] + bb); o.w = f2bf(v[3] + bb);
            *(short4*)&tv[(c & 127) * 264 + sr] = o;
          }
        }
      }
      __syncthreads();
#pragma unroll
      for (int i = 0; i < 8; ++i) {
        int chunk = i * 512 + tid;
        int h = chunk >> 5, sc = (chunk & 31) * 8;
        bf16x8 v8 = *(const bf16x8*)&tv[h * 264 + sc];
        *(bf16x8*)&VT[(size_t)(hseg + p * 128 + h) * S_ + sb + sc] = v8;
      }
      __syncthreads();
    }
    return;
  }
#pragma unroll
  for (int mq = 0; mq < 8; ++mq) {
    int rowb = m0 + wr * 128 + (mq >> 2) * 64 + (mq & 3) * 16 + kg * 4;
#pragma unroll
    for (int n = 0; n < 4; ++n) {
      int col = n0 + wc * 64 + n * 16 + lr;
      f32x4 v = acc[mq][n];
      int seg = n0 >> 10;  // block-uniform: 0=Q 1=K (V intercepted above)
      const float* bp = (seg == 0) ? b0 : b1;
      short* C = (short*)((seg == 0) ? C0 : C1);
      int cl = col & 1023;
      float bb = bp[cl];
#pragma unroll
      for (int r = 0; r < 4; ++r)
        C[(size_t)(rowb + r) * ldC + cl] = f2bf(v[r] + bb);
    }
  }
}

// ============ scores: 128x128 m97-style, 256 threads, 4 blocks/CU ===========
#define MFMA16Q()                                                            \
  _Pragma("unroll")                                                          \
  for (int m = 0; m < 4; ++m) {                                              \
    _Pragma("unroll")                                                        \
    for (int n = 0; n < 4; ++n)                                              \
      acc[m][n] = __builtin_amdgcn_mfma_f32_16x16x32_bf16(                   \
          af[m], bfr[n], acc[m][n], 0, 0, 0);                                \
  }

__global__ __launch_bounds__(256, 4)
void sc128(const short* __restrict__ Q, const short* __restrict__ Kb,
           short* __restrict__ P, float* __restrict__ Pl, float scale) {
  const int z = blockIdx.x & 7;          // one batch per XCD
  int rr0 = blockIdx.x >> 3;             // 0..135 over causal (by,bx)
  int by = 0, ac = 0;
  while (rr0 >= ac + by + 1) { ac += by + 1; ++by; }
  const int bx = rr0 - ac;
  const short* A  = Q  + (size_t)z * S_ * H_;
  const short* Bt = Kb + (size_t)z * S_ * H_;

  __shared__ __align__(16) short lA[2][128 * 32];   // 16 KB
  __shared__ __align__(16) short lB[2][128 * 32];   // 16 KB
  const char* lAp = (const char*)&lA[0][0];
  const char* lBp = (const char*)&lB[0][0];

  const int tid = threadIdx.x;
  const int lane = tid & 63;
  const int wv = tid >> 6;               // 0..3
  const int wr = wv >> 1, wc = wv & 1;   // 2M x 2N, wave tile 64x64
  const int lr = lane & 15, kg = lane >> 4;
  const int m0 = by * 128, n0 = bx * 128;

  const int aCol = (kg * 16) ^ ((lr & 8) << 2);
  const int srow = tid >> 2;                               // 0..63
  const int scol = (((tid & 3) * 16) ^ (tid & 32)) >> 1;

  f32x4 acc[4][4];
#pragma unroll
  for (int m = 0; m < 4; ++m)
#pragma unroll
    for (int n = 0; n < 4; ++n) acc[m][n] = (f32x4){0.f, 0.f, 0.f, 0.f};
  bf16x8 bfr[4], af[4];

  for (int t = 0; t < 16; ++t) {         // K = 1024
    const short* sA = A  + (size_t)(m0 + srow) * H_ + t * 64 + scol;
    const short* sB = Bt + (size_t)(n0 + srow) * H_ + t * 64 + scol;
#pragma unroll
    for (int ks = 0; ks < 2; ++ks) {
      char* dA = (char*)lAp + ks * 8192 + tid * 16;
      char* dB = (char*)lBp + ks * 8192 + tid * 16;
      async16(sA + ks * 32, dA);
      async16(sA + ks * 32 + (size_t)64 * H_, dA + 4096);
      async16(sB + ks * 32, dB);
      async16(sB + ks * 32 + (size_t)64 * H_, dB + 4096);
    }
    VMC(0);
    BAR();
#pragma unroll
    for (int ks = 0; ks < 2; ++ks) {
#pragma unroll
      for (int n = 0; n < 4; ++n)
        bfr[n] = *(const bf16x8*)(lBp + ks * 8192 +
                                  ((wc * 64 + n * 16 + lr) << 6) + aCol);
#pragma unroll
      for (int m = 0; m < 4; ++m)
        af[m] = *(const bf16x8*)(lAp + ks * 8192 +
                                 ((wr * 64 + m * 16 + lr) << 6) + aCol);
      asm volatile("s_waitcnt lgkmcnt(0)" ::: "memory");
      __builtin_amdgcn_sched_barrier(0);
      __builtin_amdgcn_s_setprio(1);
      MFMA16Q();
      __builtin_amdgcn_s_setprio(0);
    }
    BAR();
  }

  // Epilogue: P = exp(s) bf16 (masked on diag tile) + row-sum partial
  float* tmpL = (float*)lAp;                 // [128][2]
  short* C = P + (size_t)z * S_ * S_;
  const bool diag = (bx == by);
#pragma unroll
  for (int m = 0; m < 4; ++m) {
    int rt0 = wr * 64 + m * 16 + kg * 4;
#pragma unroll
    for (int r = 0; r < 4; ++r) {
      int rt = rt0 + r;
      float se = 0.f;
#pragma unroll
      for (int n = 0; n < 4; ++n) {
        int c = wc * 64 + n * 16 + lr;
        bool ok = !diag || (c <= rt);
        short sh = ok ? f2bf(__expf(acc[m][n][r] * scale)) : (short)0;
        se += bf2f(sh);
        C[(size_t)(m0 + rt) * S_ + n0 + c] = sh;
      }
#pragma unroll
      for (int o = 1; o < 16; o <<= 1) se += __shfl_xor(se, o);
      if (lr == 0) tmpL[rt * 2 + wc] = se;
    }
  }
  __syncthreads();
  if (tid < 128) {
    float l = tmpL[tid * 2 + 0] + tmpL[tid * 2 + 1];
    Pl[((size_t)z * 16 + bx) * S_ + m0 + tid] = l;
  }
}

// ====== PV: 128x128 m97-style, 4 blocks/CU, all-resident balanced quads =====
// Grid 1024 = 8z x 8bx x 16by (exactly 4 blocks/CU, all co-resident).
// by = (j<8)?(15-j):(j-8) with j=rr0>>3: co-resident quads {j,j+4,j+8,j+12}
// have by+1 sums == 34 -> per-CU K-work exactly constant. K = (by+1)*128.
// Out fp32 * (1/l) from 128-col Pl partials.
__global__ __launch_bounds__(256, 4)
void pv128q(const short* __restrict__ A, const short* __restrict__ Bt,
            float* __restrict__ C0, const float* __restrict__ Pl) {
  const int z = blockIdx.x & 7;          // one batch per XCD
  const int rr0 = blockIdx.x >> 3;       // 0..127
  const int bx = rr0 & 7;
  const int j = rr0 >> 3;                // 0..15
  const int by = (j < 8) ? (15 - j) : (j - 8);
  const short* Ap  = A  + (size_t)z * S_ * S_;
  const short* Btp = Bt + (size_t)z * H_ * S_;

  __shared__ __align__(16) short lA[2][128 * 32];   // 16 KB
  __shared__ __align__(16) short lB[2][128 * 32];   // 16 KB
  __shared__ float sLi[128];
  const char* lAp = (const char*)&lA[0][0];
  const char* lBp = (const char*)&lB[0][0];

  const int tid = threadIdx.x;
  const int lane = tid & 63;
  const int wv = tid >> 6;               // 0..3
  const int wr = wv >> 1, wc = wv & 1;   // 2M x 2N, wave tile 64x64
  const int lr = lane & 15, kg = lane >> 4;
  const int m0 = by * 128, n0 = bx * 128;
  const int nt = (by + 1) * 2;           // K = (by+1)*128, BK=64

  const int aCol = (kg * 16) ^ ((lr & 8) << 2);
  const int srow = tid >> 2;                               // 0..63
  const int scol = (((tid & 3) * 16) ^ (tid & 32)) >> 1;

  if (tid < 128) {                       // per-row 1/l from 128-col partials
    float l = 0.f;
    for (int kt = 0; kt <= by; ++kt)
      l += Pl[((size_t)z * 16 + kt) * S_ + m0 + tid];
    sLi[tid] = 1.f / l;
  }

  f32x4 acc[4][4];
#pragma unroll
  for (int m = 0; m < 4; ++m)
#pragma unroll
    for (int n = 0; n < 4; ++n) acc[m][n] = (f32x4){0.f, 0.f, 0.f, 0.f};
  bf16x8 bfr[4], af[4];

  for (int t = 0; t < nt; ++t) {
    const short* sA = Ap  + (size_t)(m0 + srow) * S_ + t * 64 + scol;
    const short* sB = Btp + (size_t)(n0 + srow) * S_ + t * 64 + scol;
#pragma unroll
    for (int ks = 0; ks < 2; ++ks) {
      char* dA = (char*)lAp + ks * 8192 + tid * 16;
      char* dB = (char*)lBp + ks * 8192 + tid * 16;
      async16(sA + ks * 32, dA);
      async16(sA + ks * 32 + (size_t)64 * S_, dA + 4096);
      async16(sB + ks * 32, dB);
      async16(sB + ks * 32 + (size_t)64 * S_, dB + 4096);
    }
    VMC(0);
    BAR();
#pragma unroll
    for (int ks = 0; ks < 2; ++ks) {
#pragma unroll
      for (int n = 0; n < 4; ++n)
        bfr[n] = *(const bf16x8*)(lBp + ks * 8192 +
                                  ((wc * 64 + n * 16 + lr) << 6) + aCol);
#pragma unroll
      for (int m = 0; m < 4; ++m)
        af[m] = *(const bf16x8*)(lAp + ks * 8192 +
                                 ((wr * 64 + m * 16 + lr) << 6) + aCol);
      asm volatile("s_waitcnt lgkmcnt(0)" ::: "memory");
      __builtin_amdgcn_sched_barrier(0);
      __builtin_amdgcn_s_setprio(1);
      MFMA16Q();
      __builtin_amdgcn_s_setprio(0);
    }
    BAR();
  }

  // Epilogue: scale by 1/l, fp32 final write
  float* C = C0 + (size_t)z * S_ * H_;
#pragma unroll
  for (int m = 0; m < 4; ++m) {
    int rl = wr * 64 + m * 16 + kg * 4;
    f32x4 liv = *(const f32x4*)&sLi[rl];
    int rowb = m0 + rl;
#pragma unroll
    for (int n = 0; n < 4; ++n) {
      int col = n0 + wc * 64 + n * 16 + lr;
      f32x4 v = acc[m][n];
#pragma unroll
      for (int r = 0; r < 4; ++r)
        C[(size_t)(rowb + r) * H_ + col] = v[r] * liv[r];
    }
  }
}

extern "C" void kernel_launch(void* const* d_in, const int* in_sizes, int n_in,
                              void* d_out, int out_size, void* d_ws, size_t ws_size,
                              hipStream_t stream) {
  const float* X  = (const float*)d_in[0];
  const float* Wq = (const float*)d_in[1];
  const float* bq = (const float*)d_in[2];
  const float* Wk = (const float*)d_in[3];
  const float* bk = (const float*)d_in[4];
  const float* Wv = (const float*)d_in[5];
  const float* bv = (const float*)d_in[6];

  // Workspace layout (~166.3 MB), overlays:
  //   [0,64MB)   P bf16 [B][S][S]  -- early: Xbf [0,32MB)
  //   [64,96)    Q bf16, [96,128) K bf16, [128,160) Vt bf16
  //   [160,166.3) Wt bf16 x3 (proj only) -- later: row-sum partials Pl
  char* ws = (char*)d_ws;
  const size_t MB = 1024ull * 1024ull;
  short* Pbuf = (short*)ws;
  short* Xbf  = (short*)ws;
  short* Q    = (short*)(ws + 64 * MB);
  short* Kb   = (short*)(ws + 96 * MB);
  short* Vt   = (short*)(ws + 128 * MB);
  short* Wt   = (short*)(ws + 160 * MB);
  float* Pl   = (float*)(ws + 160 * MB);   // [z*16+kt128][2048] f32 = 1 MB

  // 1) prep: X -> bf16 + W -> W^T bf16, one launch
  prep<<<2816, 256, 0, stream>>>(X, Xbf, Wq, Wk, Wv, Wt);
  // 2) fused QKV projection (8-phase dbuf, (512,2)); V transposed to Vt
  gemm8<<<768, 512, 0, stream>>>(
      Xbf, Wt, Q, Kb, Vt, bq, bk, bv, E_, E_, E_, H_);
  // 3) P = exp(Q K^T / 32) bf16 + 128-col row-sum partials (1088 = 136 x 8)
  sc128<<<1088, 256, 0, stream>>>(Q, Kb, Pbuf, Pl, 0.03125f);
  // 4) out = (P @ V) * (1/l) fp32 (1024 all-resident, balanced quads)
  pv128q<<<1024, 256, 0, stream>>>(Pbuf, Vt, (float*)d_out, Pl);
}